// Round 2
// 137.584 us; speedup vs baseline: 1.0080x; 1.0080x over previous
//
#include <hip/hip_runtime.h>
#include <stdint.h>

// MPS chain contraction, B=32768, L=256, D=16.
// R9 == R8 resubmit (R8 bench died with an infra error, no counters).
// R8: counted-vmcnt pipeline (T3/T4) on the R7 pair-product structure.
//   - frag LDS quad-buffered per PAIR (frag[2][4][4][64], 32 KB), 3-pair
//     prefetch depth; each half-wave DMAs 2 of the 4 combos per pair.
//   - raw s_barrier + s_waitcnt vmcnt(5) per pair-epoch; the main loop
//     NEVER drains vmcnt to 0, so prefetched global_load_lds stay in
//     flight across barriers (the old __syncthreads drained the
//     just-issued chunk every iteration -> ~4500 cy/chunk wall).
//   - phi staging issued 2 chunks ahead (wave-local, own-vmcnt ordered).
//   - s_setprio(1) around the 8-MFMA cluster.
// Issue order per chunk: [A: frag(2c+3) x2] [B: phi(c+2), frag(2c+4) x2]
// => uniform vmcnt(5) guarantees pair-j frags + chunk-c phi have landed.

typedef short  bf16x8 __attribute__((ext_vector_type(8)));
typedef float  f32x4  __attribute__((ext_vector_type(4)));
typedef int    i32x4  __attribute__((ext_vector_type(4)));
typedef unsigned int u32;

#define NPF 64
#define NPB 63
#define BWD_OFF (NPF*4*64)   // i32x4 units
#define NCHUNK 32

#define PACK_HI(hi, lo) ((int)__builtin_amdgcn_perm((u32)(hi), (u32)(lo), 0x07060302u))

__device__ __forceinline__ u32 rne_bump(u32 u){ return u + 0x7FFFu + ((u >> 16) & 1u); }

__device__ __forceinline__ void async16(const void* g, void* l){
  __builtin_amdgcn_global_load_lds(
    (const __attribute__((address_space(1))) u32*)(uintptr_t)g,
    (__attribute__((address_space(3))) u32*)(uintptr_t)l, 16, 0, 0);
}

// Pair-fragment table: blocks 0..63 fwd (j=bid), 64..126 bwd (j=bid-64).
// fwd: G[m][cq] = sum_r Ca[cq][p][r]*Cb[r][q][m],  Ca=cm[2j], Cb=cm[2j+1]
// bwd: G[m][cq] = sum_r Ca[m][p][r]*Cb[r][q][cq],  Ca=cm[252-2j], Cb=cm[253-2j]
// lane (m=lane&15, g=lane>>4) packs cols 4g..4g+3 hi (dw0,1) and lo (dw2,3).
__global__ void build_pair_frags(const float* __restrict__ cm, i32x4* __restrict__ ws)
{
  __shared__ float Ca[512], Cb[512];   // [x][p][y] = cm[t][x][p][y]
  const int bid = blockIdx.x;
  const bool fwd = bid < NPF;
  const int j  = fwd ? bid : bid - NPF;
  const int ta = fwd ? 2*j     : 252 - 2*j;
  const int tb = fwd ? 2*j + 1 : 253 - 2*j;
  {
    const float* A = cm + ta*512;
    const float* B = cm + tb*512;
    for (int i = threadIdx.x; i < 512; i += 256){ Ca[i] = A[i]; Cb[i] = B[i]; }
  }
  __syncthreads();
  const int f    = threadIdx.x >> 6;    // combo p*2+q
  const int lane = threadIdx.x & 63;
  const int m    = lane & 15;
  const int g    = lane >> 4;
  const int p    = f >> 1, q = f & 1;
  u32 hi[4], lo[4];
  #pragma unroll
  for (int x = 0; x < 4; ++x){
    const int cq = 4*g + x;
    float acc = 0.f;
    #pragma unroll
    for (int r = 0; r < 16; ++r){
      const float a = fwd ? Ca[cq*32 + p*16 + r] : Ca[m*32 + p*16 + r];
      const float b = fwd ? Cb[r*32 + q*16 + m]  : Cb[r*32 + q*16 + cq];
      acc = fmaf(a, b, acc);
    }
    const u32 u  = __float_as_uint(acc);
    const u32 aa = rne_bump(u);
    const float hf = __uint_as_float(aa & 0xFFFF0000u);
    const u32 bb = rne_bump(__float_as_uint(acc - hf));
    hi[x] = aa >> 16; lo[x] = bb >> 16;
  }
  i32x4 w;
  w[0] = (int)(hi[0] | (hi[1] << 16));
  w[1] = (int)(hi[2] | (hi[3] << 16));
  w[2] = (int)(lo[0] | (lo[1] << 16));
  w[3] = (int)(lo[2] | (lo[3] << 16));
  ws[(fwd ? 0 : BWD_OFF) + (j*4 + f)*64 + lane] = w;
}

__global__ __launch_bounds__(256, 4) void mps_chain(
  const float* __restrict__ phi,
  const float* __restrict__ core_first,
  const float* __restrict__ core_last,
  const float* __restrict__ bias,
  const i32x4* __restrict__ ws,
  float* __restrict__ out)
{
  const int lane = threadIdx.x & 63;
  const int wv   = threadIdx.x >> 6;
  const int b0   = blockIdx.x * 32;
  const int n    = lane & 15;            // sample column
  const int g    = lane >> 4;            // holds rows 4g..4g+3
  const int half = wv & 1;
  const int s_in = half*16 + n;
  const bool isFwd = (wv < 2);
  const int dirIdx = isFwd ? 0 : 1;

  // LDS: frags 32 KB (quad-buffered per pair) + phi 8 KB = 40 KB -> 4 blocks/CU
  __shared__ i32x4 frag[2][4][4][64];        // [dir][buf=pair&3][combo][lane]
  __shared__ float phL[2][2][2][4][16][4];   // [dir][buf][k=half][qt][sloc][e]

  const float* phiRow = phi + (size_t)(b0 + s_in) * 512;

  // phi DMA source (transposed lane map: sloc=lane&15 -> sample, qt=lane>>4)
  const float* phiDma = phi + (size_t)(b0 + 16*half + (lane & 15)) * 512
                            + (lane >> 4) * 4;
  const i32x4* wsD = isFwd ? ws : (ws + BWD_OFF);
  const int maxPr  = isFwd ? NPF - 1 : NPB - 1;
  // per-lane source base for this wave's two combos (2*half, 2*half+1)
  const i32x4* wsLane = wsD + (2*half)*64 + lane;

  auto FRAG = [&](int j){
    const int pr = j > maxPr ? maxPr : j;     // clamp source, keep buf rotation
    const i32x4* s = wsLane + pr*256;
    i32x4* d = &frag[dirIdx][j & 3][2*half][0];
    async16(s,      d);
    async16(s + 64, d + 64);
  };
  auto PHI = [&](int cn){
    const int W = isFwd ? 4*cn : (248 - 4*cn);   // 8-idx window start
    async16(phiDma + 2*W, &phL[dirIdx][cn & 1][half][0][0][0]);
  };

  float v[4];
  i32x4 bfr;

  auto make_bfrag = [&](){
    const u32 u0 = __float_as_uint(v[0]), u1 = __float_as_uint(v[1]);
    const u32 u2 = __float_as_uint(v[2]), u3 = __float_as_uint(v[3]);
    const float l0 = v[0] - __uint_as_float(u0 & 0xFFFF0000u);
    const float l1 = v[1] - __uint_as_float(u1 & 0xFFFF0000u);
    const float l2 = v[2] - __uint_as_float(u2 & 0xFFFF0000u);
    const float l3 = v[3] - __uint_as_float(u3 & 0xFFFF0000u);
    bfr[0] = PACK_HI(u1, u0);
    bfr[1] = PACK_HI(u3, u2);
    bfr[2] = PACK_HI(__float_as_uint(l1), __float_as_uint(l0));
    bfr[3] = PACK_HI(__float_as_uint(l3), __float_as_uint(l2));
  };

  auto pair_step = [&](const i32x4* Gb, float2 cA, float2 cB){
    const i32x4 G0 = Gb[0];
    const i32x4 G1 = Gb[64];
    const i32x4 G2 = Gb[128];
    const i32x4 G3 = Gb[192];
    const float c00 = cA.x*cB.x, c01 = cA.x*cB.y;
    const float c10 = cA.y*cB.x, c11 = cA.y*cB.y;
    i32x4 sw; sw[0]=bfr[2]; sw[1]=bfr[3]; sw[2]=bfr[0]; sw[3]=bfr[1];
    const bf16x8 bh = __builtin_bit_cast(bf16x8, bfr);
    const bf16x8 bs = __builtin_bit_cast(bf16x8, sw);
    const f32x4 z = {0.f,0.f,0.f,0.f};
    __builtin_amdgcn_s_setprio(1);
    f32x4 a00 = __builtin_amdgcn_mfma_f32_16x16x32_bf16(__builtin_bit_cast(bf16x8,G0), bh, z, 0,0,0);
    a00 = __builtin_amdgcn_mfma_f32_16x16x32_bf16(__builtin_bit_cast(bf16x8,G0), bs, a00, 0,0,0);
    f32x4 a01 = __builtin_amdgcn_mfma_f32_16x16x32_bf16(__builtin_bit_cast(bf16x8,G1), bh, z, 0,0,0);
    a01 = __builtin_amdgcn_mfma_f32_16x16x32_bf16(__builtin_bit_cast(bf16x8,G1), bs, a01, 0,0,0);
    f32x4 a10 = __builtin_amdgcn_mfma_f32_16x16x32_bf16(__builtin_bit_cast(bf16x8,G2), bh, z, 0,0,0);
    a10 = __builtin_amdgcn_mfma_f32_16x16x32_bf16(__builtin_bit_cast(bf16x8,G2), bs, a10, 0,0,0);
    f32x4 a11 = __builtin_amdgcn_mfma_f32_16x16x32_bf16(__builtin_bit_cast(bf16x8,G3), bh, z, 0,0,0);
    a11 = __builtin_amdgcn_mfma_f32_16x16x32_bf16(__builtin_bit_cast(bf16x8,G3), bs, a11, 0,0,0);
    __builtin_amdgcn_s_setprio(0);
    #pragma unroll
    for (int i2 = 0; i2 < 4; ++i2)
      v[i2] = c00*a00[i2] + c01*a01[i2] + c10*a10[i2] + c11*a11[i2];
    make_bfrag();
  };

  // ---- init ----
  if (isFwd){
    const float2 ph0 = *(const float2*)phiRow;               // phi[0]
    #pragma unroll
    for (int reg = 0; reg < 4; ++reg){
      const int r = g*4 + reg;
      v[reg] = ph0.x * core_first[r] + ph0.y * core_first[16 + r];
    }
  } else {
    const float2 phL2 = *(const float2*)(phiRow + 510);      // phi[255]
    #pragma unroll
    for (int reg = 0; reg < 4; ++reg){
      const int r = g*4 + reg;
      v[reg] = phL2.x * core_last[2*r] + phL2.y * core_last[2*r + 1];
    }
  }
  make_bfrag();

  // ---- prologue: P(0), F(0), F(1), P(1), F(2) -- matches steady-state order
  PHI(0); FRAG(0); FRAG(1); PHI(1); FRAG(2);
  __builtin_amdgcn_sched_barrier(0);

  #pragma unroll 1
  for (int c = 0; c < NCHUNK; ++c){
    const int bufp = c & 1;

    // ---- epoch A: pair 2c ----
    asm volatile("s_waitcnt vmcnt(5)" ::: "memory");
    __builtin_amdgcn_sched_barrier(0);
    __builtin_amdgcn_s_barrier();
    __builtin_amdgcn_sched_barrier(0);

    // coefficients from staged phi window (wave-local buffer, own-vmcnt safe)
    const float* pb = &phL[dirIdx][bufp][half][0][n][0];
    const float2 xA0 = *(const float2*)(pb + (isFwd ?   2 : 130));  // f2,3 | f10,11
    const float2 xB0 = *(const float2*)(pb + (isFwd ?  64 : 192));  // f4,5 | f12,13
    const float2 xA1 = *(const float2*)(pb + 66);                   // f6,7
    const float2 xB1 = *(const float2*)(pb + 128);                  // f8,9

    pair_step(&frag[dirIdx][(2*c) & 3][0][lane], xA0, xB0);
    FRAG(2*c + 3);
    __builtin_amdgcn_sched_barrier(0);

    // ---- epoch B: pair 2c+1 ----
    asm volatile("s_waitcnt vmcnt(5)" ::: "memory");
    __builtin_amdgcn_sched_barrier(0);
    __builtin_amdgcn_s_barrier();
    __builtin_amdgcn_sched_barrier(0);

    if (isFwd || (2*c + 1) < NPB)
      pair_step(&frag[dirIdx][(2*c + 1) & 3][0][lane], xA1, xB1);
    PHI(c + 2);
    FRAG(2*c + 4);
    __builtin_amdgcn_sched_barrier(0);
  }

  __syncthreads();   // full drain before LDS reuse (also retires clamped DMAs)

  // ---- epilogue: reuse frag LDS as reduction buffer ----
  float* red = (float*)&frag[0][0][0][0];        // 64 rows x 20 floats
  *(float4*)&red[(dirIdx*32 + s_in)*20 + 4*g] =
      make_float4(v[0], v[1], v[2], v[3]);
  __syncthreads();
  if (threadIdx.x < 32){
    const int s = threadIdx.x;
    float acc = bias[0];
    #pragma unroll
    for (int qq = 0; qq < 16; ++qq)
      acc += red[s*20 + qq] * red[(32 + s)*20 + qq];
    out[b0 + s] = acc;
  }
}

extern "C" void kernel_launch(void* const* d_in, const int* in_sizes, int n_in,
                              void* d_out, int out_size, void* d_ws, size_t ws_size,
                              hipStream_t stream)
{
  const float* phi  = (const float*)d_in[0];  // [32768,256,2]
  const float* cf   = (const float*)d_in[1];  // [2,16]
  const float* cm   = (const float*)d_in[2];  // [254,16,2,16]
  const float* cl   = (const float*)d_in[3];  // [16,2]
  const float* bias = (const float*)d_in[4];  // scalar
  i32x4* ws = (i32x4*)d_ws;                   // (64+63)*4*64*16B = 508 KB

  build_pair_frags<<<NPF + NPB, 256, 0, stream>>>(cm, ws);
  mps_chain<<<1024, 256, 0, stream>>>(phi, cf, cl, bias, ws, (float*)d_out);
}